// Round 3
// baseline (125.604 us; speedup 1.0000x reference)
//
#include <hip/hip_runtime.h>
#include <stdint.h>

// ---------- types ----------
typedef __attribute__((ext_vector_type(8))) __bf16 fragAB;  // 8 bf16 = 4 VGPR
typedef __attribute__((ext_vector_type(4))) float f32x4;

__device__ __forceinline__ unsigned short f2bf(float f) {
    union { float f; unsigned int u; } v; v.f = f;
    unsigned int u = v.u + 0x7fffu + ((v.u >> 16) & 1u);   // RNE
    return (unsigned short)(u >> 16);
}

__device__ __forceinline__ f32x4 MFMA(fragAB a, fragAB b, f32x4 c) {
    return __builtin_amdgcn_mfma_f32_16x16x32_bf16(a, b, c, 0, 0, 0);
}

// async global->LDS, 16B per lane; LDS dest = wave-uniform base + lane*16
__device__ __forceinline__ void gl16(const void* g, void* l) {
    __builtin_amdgcn_global_load_lds((const __attribute__((address_space(1))) void*)g,
                                     (__attribute__((address_space(3))) void*)l, 16, 0, 0);
}

__device__ __forceinline__ float fsin_rev(float rev) {   // sin(2*pi*rev)
    float r; asm("v_sin_f32 %0, %1" : "=v"(r) : "v"(rev)); return r;
}
__device__ __forceinline__ unsigned int cvtpk(float lo, float hi) {  // 2xbf16 RNE
    unsigned int r; asm("v_cvt_pk_bf16_f32 %0, %1, %2" : "=v"(r) : "v"(lo), "v"(hi)); return r;
}

// ---------- fused fp32 -> bf16 convert (x + 4 weights in one launch) ----------
__global__ __launch_bounds__(256) void cvt_all(
    const float* __restrict__ x,  const float* __restrict__ wq, const float* __restrict__ wk,
    const float* __restrict__ wv, const float* __restrict__ wo,
    unsigned short* __restrict__ xb,  unsigned short* __restrict__ wqb, unsigned short* __restrict__ wkb,
    unsigned short* __restrict__ wvb, unsigned short* __restrict__ wob)
{
    const int bid = blockIdx.x;
    const float* s; unsigned short* d; int off;
    if (bid < 4096)      { s = x;  d = xb;  off = bid; }
    else if (bid < 5120) { s = wq; d = wqb; off = bid - 4096; }
    else if (bid < 6144) { s = wk; d = wkb; off = bid - 5120; }
    else if (bid < 7168) { s = wv; d = wvb; off = bid - 6144; }
    else                 { s = wo; d = wob; off = bid - 7168; }
    const int i = (off * 256 + threadIdx.x) * 4;
    float4 f = *(const float4*)(s + i);
    ushort4 o;
    o.x = f2bf(f.x); o.y = f2bf(f.y); o.z = f2bf(f.z); o.w = f2bf(f.w);
    *(ushort4*)(d + i) = o;
}

// ---------- GEMM (m97 structure): C(4096x1024) = A * W^T + bias ----------
__global__ __launch_bounds__(256, 2)
void gemm_k(const unsigned short* __restrict__ A,
            const unsigned short* __restrict__ W0, const unsigned short* __restrict__ W1,
            const unsigned short* __restrict__ W2,
            const float* __restrict__ b0, const float* __restrict__ b1, const float* __restrict__ b2,
            void* o0, void* o1, void* o2, int md0, int md1, int md2)
{
    __shared__ unsigned short As[8192];   // [128][64] linear, 16KB
    __shared__ unsigned short Ws[8192];

    const int z = blockIdx.z;
    const unsigned short* W = z == 0 ? W0 : (z == 1 ? W1 : W2);
    const float* bias        = z == 0 ? b0 : (z == 1 ? b1 : b2);
    void* out                = z == 0 ? o0 : (z == 1 ? o1 : o2);
    const int mode           = z == 0 ? md0 : (z == 1 ? md1 : md2);

    const int t = threadIdx.x;
    const int lane = t & 63;
    const int g = lane >> 4;
    const int c = lane & 15;
    const int w = t >> 6;
    const int wm = (w >> 1) * 64;
    const int wn = (w & 1) * 64;
    const int m0 = blockIdx.y * 128;
    const int n0 = blockIdx.x * 128;

    const int srow = lane >> 3;
    const int scol = (lane & 7) * 8;

    const f32x4 zz = {0.f, 0.f, 0.f, 0.f};
    f32x4 acc[4][4];
#pragma unroll
    for (int mi = 0; mi < 4; ++mi)
#pragma unroll
        for (int ni = 0; ni < 4; ++ni) acc[mi][ni] = zz;

    for (int kt = 0; kt < 16; ++kt) {
        const int k0 = kt * 64;
#pragma unroll
        for (int r = 0; r < 4; ++r) {
            gl16(A + (size_t)(m0 + 32 * w + 8 * r + srow) * 1024 + k0 + scol,
                 (unsigned short*)As + (w * 4 + r) * 512);
            gl16(W + (size_t)(n0 + 32 * w + 8 * r + srow) * 1024 + k0 + scol,
                 (unsigned short*)Ws + (w * 4 + r) * 512);
        }
        __syncthreads();
#pragma unroll
        for (int kk = 0; kk < 2; ++kk) {
            fragAB af[4], bfr[4];
#pragma unroll
            for (int mi = 0; mi < 4; ++mi)
                af[mi] = *(const fragAB*)((char*)As + (wm + mi * 16 + c) * 128 + kk * 64 + g * 16);
#pragma unroll
            for (int ni = 0; ni < 4; ++ni)
                bfr[ni] = *(const fragAB*)((char*)Ws + (wn + ni * 16 + c) * 128 + kk * 64 + g * 16);
#pragma unroll
            for (int mi = 0; mi < 4; ++mi)
#pragma unroll
                for (int ni = 0; ni < 4; ++ni)
                    acc[mi][ni] = MFMA(af[mi], bfr[ni], acc[mi][ni]);
        }
        __syncthreads();
    }

    float bv[4];
#pragma unroll
    for (int ni = 0; ni < 4; ++ni) bv[ni] = bias[n0 + wn + ni * 16 + c];

    if (mode == 0) {
        unsigned short* C = (unsigned short*)out;
#pragma unroll
        for (int mi = 0; mi < 4; ++mi)
#pragma unroll
            for (int ni = 0; ni < 4; ++ni)
#pragma unroll
                for (int j = 0; j < 4; ++j) {
                    const int grow = m0 + wm + mi * 16 + g * 4 + j;
                    const int gcol = n0 + wn + ni * 16 + c;
                    C[(size_t)grow * 1024 + gcol] = f2bf(acc[mi][ni][j] + bv[ni]);
                }
    } else if (mode == 1) {
        unsigned short* Vt = (unsigned short*)out;   // Vt[b][n][s]
#pragma unroll
        for (int mi = 0; mi < 4; ++mi)
#pragma unroll
            for (int ni = 0; ni < 4; ++ni) {
                const int gcol = n0 + wn + ni * 16 + c;
                const int mrow = m0 + wm + mi * 16 + g * 4;
                const int bb = mrow >> 11;
                const int s = mrow & 2047;
                ushort4 pk;
                pk.x = f2bf(acc[mi][ni][0] + bv[ni]);
                pk.y = f2bf(acc[mi][ni][1] + bv[ni]);
                pk.z = f2bf(acc[mi][ni][2] + bv[ni]);
                pk.w = f2bf(acc[mi][ni][3] + bv[ni]);
                *(ushort4*)(Vt + ((size_t)bb * 1024 + gcol) * 2048 + s) = pk;
            }
    } else {
        float* C = (float*)out;
#pragma unroll
        for (int mi = 0; mi < 4; ++mi)
#pragma unroll
            for (int ni = 0; ni < 4; ++ni)
#pragma unroll
                for (int j = 0; j < 4; ++j) {
                    const int grow = m0 + wm + mi * 16 + g * 4 + j;
                    const int gcol = n0 + wn + ni * 16 + c;
                    C[(size_t)grow * 1024 + gcol] = acc[mi][ni][j] + bv[ni];
                }
    }
}

// ---------- fused sine attention, 1-barrier never-drain pipeline ----------
// K,V triple-buffered (chunk j -> buf j%3), P double-buffered. Per iter kb:
//   issue V(kb+1),K(kb+2); QK(kb); sin+Pwrite(kb); PV(kb-1); lgkm0; vmcnt(4); barrier
// vmcnt(4) retires [V_kb, K_{kb+1}] -> every chunk retired one barrier before any
// cross-wave read. K is self-staged per wave (write rows == read rows).
#define SWZ(byteoff, row) ((byteoff) ^ (((row) & 7) << 4))
#define SIN_SC 0.5968310366f   // 3.75 / (2*pi)

__global__ __launch_bounds__(256, 2)
void attn_kernel(const unsigned short* __restrict__ Qg,
                 const unsigned short* __restrict__ Kg,
                 const unsigned short* __restrict__ Vg,   // Vt[b][n][s]
                 unsigned short* __restrict__ AO)
{
    __shared__ unsigned short Ks[3 * 4096];   // 3 x [64 k][64 d], 24KB
    __shared__ unsigned short Vs[3 * 4096];   // 3 x [64 d][64 k], 24KB
    __shared__ unsigned short Ps[2 * 8192];   // 2 x [128 q][64 k], 32KB

    const int t = threadIdx.x;
    const int lane = t & 63;
    const int g = lane >> 4;
    const int c = lane & 15;
    const int w = t >> 6;
    const int qb = blockIdx.x, h = blockIdx.y, b = blockIdx.z;
    const int qbase = qb * 128;

    char* const Ksb = (char*)Ks;
    char* const Vsb = (char*)Vs;
    char* const Psb = (char*)Ps;

    // staging: wave w writes K rows [16w,16w+16) (== rows it reads in QK) and V d-rows [16w,16w+16)
    const int rowoff = lane >> 3;
    const int col8 = (lane & 7) ^ rowoff;            // pre-swizzled source col (rule #21)
    const int ch0 = 2 * w, ch1 = 2 * w + 1;
    const unsigned short* Kg0 = Kg + (size_t)(b * 2048 + 8 * ch0 + rowoff) * 1024 + h * 64 + col8 * 8;
    const unsigned short* Kg1 = Kg + (size_t)(b * 2048 + 8 * ch1 + rowoff) * 1024 + h * 64 + col8 * 8;
    const unsigned short* Vg0 = Vg + ((size_t)b * 1024 + h * 64 + 8 * ch0 + rowoff) * 2048 + col8 * 8;
    const unsigned short* Vg1 = Vg + ((size_t)b * 1024 + h * 64 + 8 * ch1 + rowoff) * 2048 + col8 * 8;

    // Q fragments in registers (loop-invariant)
    fragAB qreg[2][8];
#pragma unroll
    for (int kk = 0; kk < 2; ++kk)
#pragma unroll
        for (int qi = 0; qi < 8; ++qi)
            qreg[kk][qi] = *(const fragAB*)(Qg + (size_t)(b * 2048 + qbase + qi * 16 + c) * 1024
                                            + h * 64 + kk * 32 + g * 8);
    asm volatile("s_waitcnt vmcnt(0)" ::: "memory");   // qreg landed; vm FIFO now empty

    // prologue issues (FIFO: K0,K0,V0,V0,K1,K1)
    {
        gl16(Kg0, (unsigned short*)Ks + ch0 * 512);
        gl16(Kg1, (unsigned short*)Ks + ch1 * 512);
        gl16(Vg0, (unsigned short*)Vs + ch0 * 512);
        gl16(Vg1, (unsigned short*)Vs + ch1 * 512);
        gl16(Kg0 + 65536, (unsigned short*)Ks + 4096 + ch0 * 512);
        gl16(Kg1 + 65536, (unsigned short*)Ks + 4096 + ch1 * 512);
    }
    asm volatile("s_waitcnt vmcnt(4)" ::: "memory");   // K0 retired (self-staged, no barrier needed)

    const f32x4 z = {0.f, 0.f, 0.f, 0.f};
    f32x4 o[2][4];
#pragma unroll
    for (int mi = 0; mi < 2; ++mi)
#pragma unroll
        for (int ni = 0; ni < 4; ++ni) o[mi][ni] = z;

    const int krow = 16 * w + c;
    const int pkbyte = (16 * w + g * 4) * 2;

    // rotating buffer indices
    int bK = 0;                     // kb % 3  (K read)
    for (int kb = 0; kb < 32; ++kb) {
        const int bKw = bK == 0 ? 2 : bK - 1;   // (kb+2) % 3  (K write)
        const int bVw = bK == 2 ? 0 : bK + 1;   // (kb+1) % 3  (V write)
        const int bVr = bKw;                    // (kb-1) % 3  (V read)

        // issue V(kb+1), K(kb+2) — wrapped mod 32 at the tail to keep vmcnt uniform
        {
            const int vn = (kb + 1) & 31;
            const int kn = (kb + 2) & 31;
            unsigned short* vl = (unsigned short*)Vs + bVw * 4096;
            unsigned short* kl = (unsigned short*)Ks + bKw * 4096;
            gl16(Vg0 + vn * 64, vl + ch0 * 512);
            gl16(Vg1 + vn * 64, vl + ch1 * 512);
            gl16(Kg0 + (size_t)kn * 65536, kl + ch0 * 512);
            gl16(Kg1 + (size_t)kn * 65536, kl + ch1 * 512);
        }

        // ---- QK(kb): St = K*Q^T, wave w owns k rows [16w,16w+16) ----
        char* const kc = Ksb + bK * 8192;
        fragAB kf0 = *(const fragAB*)(kc + SWZ(krow * 128 + g * 16, krow));
        fragAB kf1 = *(const fragAB*)(kc + SWZ(krow * 128 + 64 + g * 16, krow));
        f32x4 st[8];
#pragma unroll
        for (int qi = 0; qi < 8; ++qi) st[qi] = z;
#pragma unroll
        for (int qi = 0; qi < 8; ++qi) {
            st[qi] = MFMA(kf0, qreg[0][qi], st[qi]);
            st[qi] = MFMA(kf1, qreg[1][qi], st[qi]);
        }

        // ---- sin(kb) -> P[kb&1] ----
        char* const pw = Psb + (kb & 1) * 16384;
#pragma unroll
        for (int qi = 0; qi < 8; ++qi) {
            const int q = qi * 16 + c;
            float s0 = fsin_rev(st[qi][0] * SIN_SC);
            float s1 = fsin_rev(st[qi][1] * SIN_SC);
            float s2 = fsin_rev(st[qi][2] * SIN_SC);
            float s3 = fsin_rev(st[qi][3] * SIN_SC);
            uint2 pk;
            pk.x = cvtpk(s0, s1);
            pk.y = cvtpk(s2, s3);
            *(uint2*)(pw + SWZ(q * 128 + pkbyte, q)) = pk;
        }

        // ---- PV(kb-1): independent of sin(kb) -> MFMA/VALU overlap ----
        if (kb > 0) {
            char* const pr = Psb + ((kb - 1) & 1) * 16384;
            char* const vc = Vsb + bVr * 8192;
#pragma unroll
            for (int kk = 0; kk < 2; ++kk) {
                fragAB pf[2], vf[4];
#pragma unroll
                for (int mi = 0; mi < 2; ++mi) {
                    const int q = 32 * w + mi * 16 + c;
                    pf[mi] = *(const fragAB*)(pr + SWZ(q * 128 + kk * 64 + g * 16, q));
                }
#pragma unroll
                for (int ni = 0; ni < 4; ++ni) {
                    const int dd = ni * 16 + c;
                    vf[ni] = *(const fragAB*)(vc + SWZ(dd * 128 + kk * 64 + g * 16, dd));
                }
#pragma unroll
                for (int mi = 0; mi < 2; ++mi)
#pragma unroll
                    for (int ni = 0; ni < 4; ++ni)
                        o[mi][ni] = MFMA(pf[mi], vf[ni], o[mi][ni]);
            }
        }

        asm volatile("s_waitcnt lgkmcnt(0)" ::: "memory");  // P writes visible
        asm volatile("s_waitcnt vmcnt(4)" ::: "memory");    // retire V_kb, K_{kb+1}
        __builtin_amdgcn_s_barrier();

        bK = bK == 2 ? 0 : bK + 1;
    }

    // epilogue: PV(31)  (P buf 1, V buf 31%3=1; retired+barrier'd above)
    {
        char* const pr = Psb + 16384;
        char* const vc = Vsb + 8192;
#pragma unroll
        for (int kk = 0; kk < 2; ++kk) {
            fragAB pf[2], vf[4];
#pragma unroll
            for (int mi = 0; mi < 2; ++mi) {
                const int q = 32 * w + mi * 16 + c;
                pf[mi] = *(const fragAB*)(pr + SWZ(q * 128 + kk * 64 + g * 16, q));
            }
#pragma unroll
            for (int ni = 0; ni < 4; ++ni) {
                const int dd = ni * 16 + c;
                vf[ni] = *(const fragAB*)(vc + SWZ(dd * 128 + kk * 64 + g * 16, dd));
            }
#pragma unroll
            for (int mi = 0; mi < 2; ++mi)
#pragma unroll
                for (int ni = 0; ni < 4; ++ni)
                    o[mi][ni] = MFMA(pf[mi], vf[ni], o[mi][ni]);
        }
    }

#pragma unroll
    for (int mi = 0; mi < 2; ++mi)
#pragma unroll
        for (int ni = 0; ni < 4; ++ni) {
            const int dd = ni * 16 + c;
#pragma unroll
            for (int j = 0; j < 4; ++j) {
                const int q = qbase + 32 * w + mi * 16 + g * 4 + j;
                AO[(size_t)(b * 2048 + q) * 1024 + h * 64 + dd] = f2bf(o[mi][ni][j]);
            }
        }
}

// ---------- launcher ----------
extern "C" void kernel_launch(void* const* d_in, const int* in_sizes, int n_in,
                              void* d_out, int out_size, void* d_ws, size_t ws_size,
                              hipStream_t stream) {
    (void)in_sizes; (void)n_in; (void)out_size; (void)ws_size;
    const float* x  = (const float*)d_in[0];
    const float* Wq = (const float*)d_in[1];
    const float* bq = (const float*)d_in[2];
    const float* Wk = (const float*)d_in[3];
    const float* bk = (const float*)d_in[4];
    const float* Wv = (const float*)d_in[5];
    const float* bv = (const float*)d_in[6];
    const float* Wo = (const float*)d_in[7];
    const float* bo = (const float*)d_in[8];

    char* ws = (char*)d_ws;
    unsigned short* xb  = (unsigned short*)(ws);                    // 8MB
    unsigned short* Wqb = (unsigned short*)(ws + (8u  << 20));      // 2MB each
    unsigned short* Wkb = (unsigned short*)(ws + (10u << 20));
    unsigned short* Wvb = (unsigned short*)(ws + (12u << 20));
    unsigned short* Wob = (unsigned short*)(ws + (14u << 20));
    unsigned short* Qb  = (unsigned short*)(ws + (16u << 20));      // 8MB
    unsigned short* Kb  = (unsigned short*)(ws + (24u << 20));      // 8MB
    unsigned short* Vtb = (unsigned short*)(ws + (32u << 20));      // 8MB, [b][n][s]
    unsigned short* AO  = (unsigned short*)(ws + (40u << 20));      // 8MB

    cvt_all<<<8192, 256, 0, stream>>>(x, Wq, Wk, Wv, Wo, xb, Wqb, Wkb, Wvb, Wob);

    gemm_k<<<dim3(8, 32, 3), 256, 0, stream>>>(xb, Wqb, Wkb, Wvb, bq, bk, bv,
                                               Qb, Kb, Vtb, 0, 0, 1);

    attn_kernel<<<dim3(16, 16, 2), 256, 0, stream>>>(Qb, Kb, Vtb, AO);

    gemm_k<<<dim3(8, 32, 1), 256, 0, stream>>>(AO, Wob, Wob, Wob, bo, bo, bo,
                                               d_out, d_out, d_out, 2, 2, 2);
}

// Round 4
// 116.331 us; speedup vs baseline: 1.0797x; 1.0797x over previous
//
#include <hip/hip_runtime.h>
#include <stdint.h>

// ---------- types ----------
typedef __attribute__((ext_vector_type(8))) __bf16 fragAB;  // 8 bf16 = 4 VGPR
typedef __attribute__((ext_vector_type(4))) float f32x4;

__device__ __forceinline__ unsigned short f2bf(float f) {
    union { float f; unsigned int u; } v; v.f = f;
    unsigned int u = v.u + 0x7fffu + ((v.u >> 16) & 1u);   // RNE
    return (unsigned short)(u >> 16);
}

__device__ __forceinline__ f32x4 MFMA(fragAB a, fragAB b, f32x4 c) {
    return __builtin_amdgcn_mfma_f32_16x16x32_bf16(a, b, c, 0, 0, 0);
}

// async global->LDS, 16B per lane; LDS dest = wave-uniform base + lane*16
__device__ __forceinline__ void gl16(const void* g, void* l) {
    __builtin_amdgcn_global_load_lds((const __attribute__((address_space(1))) void*)g,
                                     (__attribute__((address_space(3))) void*)l, 16, 0, 0);
}

__device__ __forceinline__ float fsin_rev(float rev) {   // sin(2*pi*rev)
    float r; asm("v_sin_f32 %0, %1" : "=v"(r) : "v"(rev)); return r;
}
__device__ __forceinline__ unsigned int cvtpk(float lo, float hi) {  // 2xbf16 RNE
    unsigned int r; asm("v_cvt_pk_bf16_f32 %0, %1, %2" : "=v"(r) : "v"(lo), "v"(hi)); return r;
}

// ---------- fused fp32 -> bf16 convert (x + 4 weights in one launch) ----------
__global__ __launch_bounds__(256) void cvt_all(
    const float* __restrict__ x,  const float* __restrict__ wq, const float* __restrict__ wk,
    const float* __restrict__ wv, const float* __restrict__ wo,
    unsigned short* __restrict__ xb,  unsigned short* __restrict__ wqb, unsigned short* __restrict__ wkb,
    unsigned short* __restrict__ wvb, unsigned short* __restrict__ wob)
{
    const int bid = blockIdx.x;
    const float* s; unsigned short* d; int off;
    if (bid < 4096)      { s = x;  d = xb;  off = bid; }
    else if (bid < 5120) { s = wq; d = wqb; off = bid - 4096; }
    else if (bid < 6144) { s = wk; d = wkb; off = bid - 5120; }
    else if (bid < 7168) { s = wv; d = wvb; off = bid - 6144; }
    else                 { s = wo; d = wob; off = bid - 7168; }
    const int i = (off * 256 + threadIdx.x) * 4;
    float4 f = *(const float4*)(s + i);
    ushort4 o;
    o.x = f2bf(f.x); o.y = f2bf(f.y); o.z = f2bf(f.z); o.w = f2bf(f.w);
    *(ushort4*)(d + i) = o;
}

// ---------- GEMM (m97 structure, 128x128): used for Q/K/V projections ----------
__global__ __launch_bounds__(256, 2)
void gemm_k(const unsigned short* __restrict__ A,
            const unsigned short* __restrict__ W0, const unsigned short* __restrict__ W1,
            const unsigned short* __restrict__ W2,
            const float* __restrict__ b0, const float* __restrict__ b1, const float* __restrict__ b2,
            void* o0, void* o1, void* o2)
{
    __shared__ unsigned short As[8192];   // [128][64] linear, 16KB
    __shared__ unsigned short Ws[8192];

    const int z = blockIdx.z;
    const unsigned short* W = z == 0 ? W0 : (z == 1 ? W1 : W2);
    const float* bias        = z == 0 ? b0 : (z == 1 ? b1 : b2);
    void* out                = z == 0 ? o0 : (z == 1 ? o1 : o2);
    const int mode           = z == 2 ? 1 : 0;   // V -> transposed epilogue

    const int t = threadIdx.x;
    const int lane = t & 63;
    const int g = lane >> 4;
    const int c = lane & 15;
    const int w = t >> 6;
    const int wm = (w >> 1) * 64;
    const int wn = (w & 1) * 64;
    const int m0 = blockIdx.y * 128;
    const int n0 = blockIdx.x * 128;

    const int srow = lane >> 3;
    const int scol = (lane & 7) * 8;

    const f32x4 zz = {0.f, 0.f, 0.f, 0.f};
    f32x4 acc[4][4];
#pragma unroll
    for (int mi = 0; mi < 4; ++mi)
#pragma unroll
        for (int ni = 0; ni < 4; ++ni) acc[mi][ni] = zz;

    for (int kt = 0; kt < 16; ++kt) {
        const int k0 = kt * 64;
#pragma unroll
        for (int r = 0; r < 4; ++r) {
            gl16(A + (size_t)(m0 + 32 * w + 8 * r + srow) * 1024 + k0 + scol,
                 (unsigned short*)As + (w * 4 + r) * 512);
            gl16(W + (size_t)(n0 + 32 * w + 8 * r + srow) * 1024 + k0 + scol,
                 (unsigned short*)Ws + (w * 4 + r) * 512);
        }
        __syncthreads();
#pragma unroll
        for (int kk = 0; kk < 2; ++kk) {
            fragAB af[4], bfr[4];
#pragma unroll
            for (int mi = 0; mi < 4; ++mi)
                af[mi] = *(const fragAB*)((char*)As + (wm + mi * 16 + c) * 128 + kk * 64 + g * 16);
#pragma unroll
            for (int ni = 0; ni < 4; ++ni)
                bfr[ni] = *(const fragAB*)((char*)Ws + (wn + ni * 16 + c) * 128 + kk * 64 + g * 16);
#pragma unroll
            for (int mi = 0; mi < 4; ++mi)
#pragma unroll
                for (int ni = 0; ni < 4; ++ni)
                    acc[mi][ni] = MFMA(af[mi], bfr[ni], acc[mi][ni]);
        }
        __syncthreads();
    }

    float bv[4];
#pragma unroll
    for (int ni = 0; ni < 4; ++ni) bv[ni] = bias[n0 + wn + ni * 16 + c];

    if (mode == 0) {
        unsigned short* C = (unsigned short*)out;
#pragma unroll
        for (int mi = 0; mi < 4; ++mi)
#pragma unroll
            for (int ni = 0; ni < 4; ++ni)
#pragma unroll
                for (int j = 0; j < 4; ++j) {
                    const int grow = m0 + wm + mi * 16 + g * 4 + j;
                    const int gcol = n0 + wn + ni * 16 + c;
                    C[(size_t)grow * 1024 + gcol] = f2bf(acc[mi][ni][j] + bv[ni]);
                }
    } else {
        unsigned short* Vt = (unsigned short*)out;   // Vt[b][n][s]
#pragma unroll
        for (int mi = 0; mi < 4; ++mi)
#pragma unroll
            for (int ni = 0; ni < 4; ++ni) {
                const int gcol = n0 + wn + ni * 16 + c;
                const int mrow = m0 + wm + mi * 16 + g * 4;
                const int bb = mrow >> 11;
                const int s = mrow & 2047;
                ushort4 pk;
                pk.x = f2bf(acc[mi][ni][0] + bv[ni]);
                pk.y = f2bf(acc[mi][ni][1] + bv[ni]);
                pk.z = f2bf(acc[mi][ni][2] + bv[ni]);
                pk.w = f2bf(acc[mi][ni][3] + bv[ni]);
                *(ushort4*)(Vt + ((size_t)bb * 1024 + gcol) * 2048 + s) = pk;
            }
    }
}

// ---------- GEMM 64x128 tile, fp32 out: final projection (2 blocks/CU) ----------
__global__ __launch_bounds__(256, 4)
void gemm64(const unsigned short* __restrict__ A,
            const unsigned short* __restrict__ W,
            const float* __restrict__ bias, float* __restrict__ out)
{
    __shared__ unsigned short As[4096];   // [64][64]  8KB
    __shared__ unsigned short Ws[8192];   // [128][64] 16KB

    const int t = threadIdx.x;
    const int lane = t & 63;
    const int g = lane >> 4;
    const int c = lane & 15;
    const int w = t >> 6;
    const int wm = (w >> 1) * 32;
    const int wn = (w & 1) * 64;
    const int m0 = blockIdx.y * 64;
    const int n0 = blockIdx.x * 128;

    const int srow = lane >> 3;
    const int scol = (lane & 7) * 8;

    const f32x4 zz = {0.f, 0.f, 0.f, 0.f};
    f32x4 acc[2][4];
#pragma unroll
    for (int mi = 0; mi < 2; ++mi)
#pragma unroll
        for (int ni = 0; ni < 4; ++ni) acc[mi][ni] = zz;

    for (int kt = 0; kt < 16; ++kt) {
        const int k0 = kt * 64;
        // A: 64x64, wave w stages rows [16w,16w+16)
        gl16(A + (size_t)(m0 + 16 * w + srow) * 1024 + k0 + scol,
             (unsigned short*)As + (2 * w) * 512);
        gl16(A + (size_t)(m0 + 16 * w + 8 + srow) * 1024 + k0 + scol,
             (unsigned short*)As + (2 * w + 1) * 512);
        // W: 128x64, wave w stages rows [32w,32w+32)
#pragma unroll
        for (int r = 0; r < 4; ++r)
            gl16(W + (size_t)(n0 + 32 * w + 8 * r + srow) * 1024 + k0 + scol,
                 (unsigned short*)Ws + (w * 4 + r) * 512);
        __syncthreads();
#pragma unroll
        for (int kk = 0; kk < 2; ++kk) {
            fragAB af[2], bfr[4];
#pragma unroll
            for (int mi = 0; mi < 2; ++mi)
                af[mi] = *(const fragAB*)((char*)As + (wm + mi * 16 + c) * 128 + kk * 64 + g * 16);
#pragma unroll
            for (int ni = 0; ni < 4; ++ni)
                bfr[ni] = *(const fragAB*)((char*)Ws + (wn + ni * 16 + c) * 128 + kk * 64 + g * 16);
#pragma unroll
            for (int mi = 0; mi < 2; ++mi)
#pragma unroll
                for (int ni = 0; ni < 4; ++ni)
                    acc[mi][ni] = MFMA(af[mi], bfr[ni], acc[mi][ni]);
        }
        __syncthreads();
    }

#pragma unroll
    for (int ni = 0; ni < 4; ++ni) {
        const float bv = bias[n0 + wn + ni * 16 + c];
#pragma unroll
        for (int mi = 0; mi < 2; ++mi)
#pragma unroll
            for (int j = 0; j < 4; ++j) {
                const int grow = m0 + wm + mi * 16 + g * 4 + j;
                const int gcol = n0 + wn + ni * 16 + c;
                out[(size_t)grow * 1024 + gcol] = acc[mi][ni][j] + bv;
            }
    }
}

// ---------- fused sine attention: QBLK=64, 40KB LDS, 4 blocks/CU ----------
// grid 1024 flat, XCD-chunked decode. K/V double-buffered (prefetch-1 gl16,
// drained by bottom __syncthreads), P single-buffered between the 2 barriers.
#define SWZ(byteoff, row) ((byteoff) ^ (((row) & 7) << 4))
#define SIN_SC 0.5968310366f   // 3.75 / (2*pi)

__global__ __launch_bounds__(256, 4)
void attn_kernel(const unsigned short* __restrict__ Qg,
                 const unsigned short* __restrict__ Kg,
                 const unsigned short* __restrict__ Vg,   // Vt[b][n][s]
                 unsigned short* __restrict__ AO)
{
    __shared__ unsigned short Ks[2 * 4096];   // 2 x [64 k][64 d], 16KB
    __shared__ unsigned short Vs[2 * 4096];   // 2 x [64 d][64 k], 16KB
    __shared__ unsigned short Ps[4096];       // [64 q][64 k],      8KB

    const int t = threadIdx.x;
    const int lane = t & 63;
    const int g = lane >> 4;
    const int c = lane & 15;
    const int w = t >> 6;

    // XCD-chunked bijective swizzle: XCD x runs logical blocks [128x, 128x+128)
    const int bid = blockIdx.x;
    const int lb = (bid & 7) * 128 + (bid >> 3);
    const int qb = lb & 31;
    const int h = (lb >> 5) & 15;
    const int b = lb >> 9;
    const int qbase = qb * 64;

    char* const Ksb = (char*)Ks;
    char* const Vsb = (char*)Vs;
    char* const Psb = (char*)Ps;

    // staging: chunk = 8 rows x 64 cols, pre-swizzled source col (rule #21)
    const int r8 = lane >> 3;
    const int col8 = (lane & 7) ^ r8;
    const unsigned short* KgB = Kg + (size_t)(b * 2048) * 1024 + h * 64;       // + (kb*64+row)*1024 + col8*8
    const unsigned short* VtB = Vg + ((size_t)b * 1024 + h * 64) * 2048;        // + drow*2048 + kb*64 + col8*8
    const int ch0 = 2 * w, ch1 = 2 * w + 1;

    // Q fragments in registers (loop-invariant): qreg[kk][qi]
    fragAB qreg[2][4];
#pragma unroll
    for (int kk = 0; kk < 2; ++kk)
#pragma unroll
        for (int qi = 0; qi < 4; ++qi)
            qreg[kk][qi] = *(const fragAB*)(Qg + (size_t)(b * 2048 + qbase + qi * 16 + c) * 1024
                                            + h * 64 + kk * 32 + g * 8);

    // prologue: stage kb=0 into buf 0
    gl16(KgB + (size_t)(8 * ch0 + r8) * 1024 + col8 * 8, (unsigned short*)Ks + ch0 * 512);
    gl16(KgB + (size_t)(8 * ch1 + r8) * 1024 + col8 * 8, (unsigned short*)Ks + ch1 * 512);
    gl16(VtB + (size_t)(8 * ch0 + r8) * 2048 + col8 * 8, (unsigned short*)Vs + ch0 * 512);
    gl16(VtB + (size_t)(8 * ch1 + r8) * 2048 + col8 * 8, (unsigned short*)Vs + ch1 * 512);
    __syncthreads();

    const f32x4 z = {0.f, 0.f, 0.f, 0.f};
    f32x4 o[4];
#pragma unroll
    for (int ni = 0; ni < 4; ++ni) o[ni] = z;

    const int krow = 16 * w + c;                 // QK k-row == PV q-row for this wave
    const int pkbyte = (16 * w + g * 4) * 2;

    for (int kb = 0; kb < 32; ++kb) {
        const int cur = kb & 1;
        char* const kc = Ksb + cur * 8192;
        char* const vc = Vsb + cur * 8192;

        if (kb < 31) {   // prefetch next chunk into buf cur^1 (retired by bottom sync)
            const int nxt = cur ^ 1;
            unsigned short* kl = (unsigned short*)Ks + nxt * 4096;
            unsigned short* vl = (unsigned short*)Vs + nxt * 4096;
            const size_t kro = (size_t)(kb + 1) * 64;
            gl16(KgB + (kro + 8 * ch0 + r8) * 1024 + col8 * 8, kl + ch0 * 512);
            gl16(KgB + (kro + 8 * ch1 + r8) * 1024 + col8 * 8, kl + ch1 * 512);
            gl16(VtB + (size_t)(8 * ch0 + r8) * 2048 + kro + col8 * 8, vl + ch0 * 512);
            gl16(VtB + (size_t)(8 * ch1 + r8) * 2048 + kro + col8 * 8, vl + ch1 * 512);
        }

        // ---- QK: St = K*Q^T, wave w owns k rows [16w,16w+16), q 0..63 ----
        fragAB kf0 = *(const fragAB*)(kc + SWZ(krow * 128 + g * 16, krow));
        fragAB kf1 = *(const fragAB*)(kc + SWZ(krow * 128 + 64 + g * 16, krow));
        f32x4 st[4];
#pragma unroll
        for (int qi = 0; qi < 4; ++qi) st[qi] = z;
#pragma unroll
        for (int qi = 0; qi < 4; ++qi) {
            st[qi] = MFMA(kf0, qreg[0][qi], st[qi]);
            st[qi] = MFMA(kf1, qreg[1][qi], st[qi]);
        }

        // ---- P = sin(3.75*St) -> Ps[q][k] ----
#pragma unroll
        for (int qi = 0; qi < 4; ++qi) {
            const int q = qi * 16 + c;
            float s0 = fsin_rev(st[qi][0] * SIN_SC);
            float s1 = fsin_rev(st[qi][1] * SIN_SC);
            float s2 = fsin_rev(st[qi][2] * SIN_SC);
            float s3 = fsin_rev(st[qi][3] * SIN_SC);
            uint2 pk;
            pk.x = cvtpk(s0, s1);
            pk.y = cvtpk(s2, s3);
            *(uint2*)(Psb + SWZ(q * 128 + pkbyte, q)) = pk;
        }

        asm volatile("s_waitcnt lgkmcnt(0)" ::: "memory");  // P visible
        __builtin_amdgcn_s_barrier();                       // keep prefetch in flight

        // ---- O += P*V : wave w owns q rows [16w,16w+16), d 0..63 ----
#pragma unroll
        for (int kk = 0; kk < 2; ++kk) {
            fragAB pf, vf[4];
            pf = *(const fragAB*)(Psb + SWZ(krow * 128 + kk * 64 + g * 16, krow));
#pragma unroll
            for (int ni = 0; ni < 4; ++ni) {
                const int dd = ni * 16 + c;
                vf[ni] = *(const fragAB*)(vc + SWZ(dd * 128 + kk * 64 + g * 16, dd));
            }
#pragma unroll
            for (int ni = 0; ni < 4; ++ni)
                o[ni] = MFMA(pf, vf[ni], o[ni]);
        }

        __syncthreads();   // drains vmcnt: next buf staged; P readers done
    }

#pragma unroll
    for (int ni = 0; ni < 4; ++ni) {
        const int dd = ni * 16 + c;
#pragma unroll
        for (int j = 0; j < 4; ++j) {
            const int q = qbase + 16 * w + g * 4 + j;
            AO[(size_t)(b * 2048 + q) * 1024 + h * 64 + dd] = f2bf(o[ni][j]);
        }
    }
}

// ---------- launcher ----------
extern "C" void kernel_launch(void* const* d_in, const int* in_sizes, int n_in,
                              void* d_out, int out_size, void* d_ws, size_t ws_size,
                              hipStream_t stream) {
    (void)in_sizes; (void)n_in; (void)out_size; (void)ws_size;
    const float* x  = (const float*)d_in[0];
    const float* Wq = (const float*)d_in[1];
    const float* bq = (const float*)d_in[2];
    const float* Wk = (const float*)d_in[3];
    const float* bk = (const float*)d_in[4];
    const float* Wv = (const float*)d_in[5];
    const float* bv = (const float*)d_in[6];
    const float* Wo = (const float*)d_in[7];
    const float* bo = (const float*)d_in[8];

    char* ws = (char*)d_ws;
    unsigned short* xb  = (unsigned short*)(ws);                    // 8MB
    unsigned short* Wqb = (unsigned short*)(ws + (8u  << 20));      // 2MB each
    unsigned short* Wkb = (unsigned short*)(ws + (10u << 20));
    unsigned short* Wvb = (unsigned short*)(ws + (12u << 20));
    unsigned short* Wob = (unsigned short*)(ws + (14u << 20));
    unsigned short* Qb  = (unsigned short*)(ws + (16u << 20));      // 8MB
    unsigned short* Kb  = (unsigned short*)(ws + (24u << 20));      // 8MB
    unsigned short* Vtb = (unsigned short*)(ws + (32u << 20));      // 8MB, [b][n][s]
    unsigned short* AO  = (unsigned short*)(ws + (40u << 20));      // 8MB

    cvt_all<<<8192, 256, 0, stream>>>(x, Wq, Wk, Wv, Wo, xb, Wqb, Wkb, Wvb, Wob);

    gemm_k<<<dim3(8, 32, 3), 256, 0, stream>>>(xb, Wqb, Wkb, Wvb, bq, bk, bv,
                                               Qb, Kb, Vtb);

    attn_kernel<<<1024, 256, 0, stream>>>(Qb, Kb, Vtb, AO);

    gemm64<<<dim3(8, 64), 256, 0, stream>>>(AO, Wob, bo, (float*)d_out);
}